// Round 3
// baseline (494.228 us; speedup 1.0000x reference)
//
#include <hip/hip_runtime.h>
#include <hip/hip_bf16.h>

#define NPTS 2048
#define NOVER 6144
#define STEP1 1536
#define STEP2 512
#define SORTN 8192
#define HW_TOT 262144

__device__ __forceinline__ float prelu_f(float x, float a) { return x >= 0.0f ? x : a * x; }

// coarse (128x128) bilinear coords for 512-output half-pixel sampling
__device__ __forceinline__ void coarse_coords(int h, int w, float& fy, float& fx,
                                              int& y0, int& y1, int& x0, int& x1) {
  float sy = (h + 0.5f) * 0.25f - 0.5f;
  float sx = (w + 0.5f) * 0.25f - 0.5f;
  float yf = floorf(sy), xf = floorf(sx);
  fy = sy - yf; fx = sx - xf;
  int yi = (int)yf, xi = (int)xf;
  y0 = min(127, max(0, yi)); y1 = min(127, max(0, yi + 1));
  x0 = min(127, max(0, xi)); x1 = min(127, max(0, xi + 1));
}

__device__ __forceinline__ float coarse_sample(const float* __restrict__ ch, float fy, float fx,
                                               int y0, int y1, int x0, int x1) {
  float v00 = ch[(y0 << 7) + x0];
  float v01 = ch[(y0 << 7) + x1];
  float v10 = ch[(y1 << 7) + x0];
  float v11 = ch[(y1 << 7) + x1];
  return (1.0f - fy) * ((1.0f - fx) * v00 + fx * v01) + fy * ((1.0f - fx) * v10 + fx * v11);
}

// zero the f32 mask region (2*512*512 floats = 2 MB) -> 131072 uint4 stores
__global__ __launch_bounds__(256) void pr_fill_v3(uint4* __restrict__ p) {
  p[blockIdx.x * 256 + threadIdx.x] = make_uint4(0u, 0u, 0u, 0u);
}

// One block per batch: uncertainty -> bitonic top-k (val desc, idx asc) -> lin sort -> mask scatter
__global__ __launch_bounds__(1024) void pr_select_v3(const float* __restrict__ coarse,
                                                     const int* __restrict__ ridx,
                                                     int* __restrict__ lin_sorted,
                                                     float* __restrict__ mask) {
  __shared__ unsigned int   vals[SORTN];     // 32 KB: monotone f32 bits of uncertainty (u >= 0)
  __shared__ unsigned short idxs[SORTN];     // 16 KB: candidate index
  const int b = blockIdx.x;
  const int t = threadIdx.x;

  for (int i = t; i < SORTN; i += 1024) {
    unsigned v = 0u;
    if (i < NOVER) {
      int lin = ridx[i];
      int h = lin >> 9, w = lin & 511;
      float fy, fx; int y0, y1, x0, x1;
      coarse_coords(h, w, fy, fx, y0, y1, x0, x1);
      const float* cb = coarse + (((size_t)b * 3) << 14);
      float p0 = coarse_sample(cb, fy, fx, y0, y1, x0, x1);
      float p1 = coarse_sample(cb + (1 << 14), fy, fx, y0, y1, x0, x1);
      float p2 = coarse_sample(cb + (2 << 14), fy, fx, y0, y1, x0, x1);
      float m = fmaxf(p0, fmaxf(p1, p2));
      float e0 = expf(p0 - m), e1 = expf(p1 - m), e2 = expf(p2 - m);
      float s = e0 + e1 + e2;
      float q0 = e0 / s, q1 = e1 / s, q2 = e2 / s;
      // sort3 descending (exact compare/swap, no value arithmetic)
      float a0 = q0, a1 = q1, a2 = q2, tmp;
      if (a0 < a1) { tmp = a0; a0 = a1; a1 = tmp; }
      if (a1 < a2) { tmp = a1; a1 = a2; a2 = tmp; }
      if (a0 < a1) { tmp = a0; a0 = a1; a1 = tmp; }
      float u = 1.0f - (a0 - a1);     // u in (0, 1]: strictly positive, so bits > 0 = padding
      v = __float_as_uint(u);         // monotone for non-negative floats
    }
    vals[i] = v;
    idxs[i] = (unsigned short)i;
  }
  __syncthreads();

  // bitonic sort: global order (value desc, index asc); keys strictly distinct (idx unique)
  for (int k = 2; k <= SORTN; k <<= 1) {
    for (int j = k >> 1; j > 0; j >>= 1) {
      for (int i = t; i < SORTN; i += 1024) {
        int l = i ^ j;
        if (l > i) {
          unsigned vi = vals[i], vl = vals[l];
          unsigned short ii = idxs[i], il = idxs[l];
          // pref = entry-at-i should precede entry-at-l in final (desc) order
          bool pref = (vi > vl) || (vi == vl && ii < il);
          bool up = ((i & k) == 0);
          if (up ? !pref : pref) {
            vals[i] = vl; vals[l] = vi;
            idxs[i] = il; idxs[l] = ii;
          }
        }
      }
      __syncthreads();
    }
  }

  // build 2048 lin values (selected top-1536 + cov 512), scatter mask
  int* lins = (int*)vals;  // vals no longer needed; idxs[0..1535] still live (disjoint array)
  for (int i = t; i < NPTS; i += 1024) {
    int lin;
    if (i < STEP1) {
      lin = ridx[(int)idxs[i]];
    } else {
      lin = ridx[HW_TOT - STEP2 + (i - STEP1)];
    }
    mask[(size_t)b * HW_TOT + lin] = 1.0f;
    lins[i] = lin;
  }
  __syncthreads();

  // bitonic sort lins ASCENDING (2048 distinct ints)
  for (int k = 2; k <= NPTS; k <<= 1) {
    for (int j = k >> 1; j > 0; j >>= 1) {
      for (int i = t; i < NPTS; i += 1024) {
        int l = i ^ j;
        if (l > i) {
          int av = lins[i], cv = lins[l];
          bool up = ((i & k) == 0);
          if (up ? (av > cv) : (av < cv)) { lins[i] = cv; lins[l] = av; }
        }
      }
      __syncthreads();
    }
  }
  for (int i = t; i < NPTS; i += 1024) lin_sorted[b * NPTS + i] = lins[i];
}

// Fused gather (replicating the reference's flatten-concat-reshape feat layout) + 3-layer MLP
__global__ __launch_bounds__(256) void pr_mlp_v3(const float* __restrict__ fine,
                                                 const float* __restrict__ coarse,
                                                 const float* __restrict__ w1,
                                                 const float* __restrict__ w2,
                                                 const float* __restrict__ w3,
                                                 const float* __restrict__ pa,
                                                 const int* __restrict__ lin_sorted,
                                                 float* __restrict__ out) {
  __shared__ __align__(16) float xs[259][16];
  __shared__ __align__(16) float l1t[256][16];
  __shared__ __align__(16) float l2t[128][16];
  const int t = threadIdx.x;
  const int g0 = blockIdx.x * 16;
  const float a = pa[0];

  // gather: x[c] of group g == featflat[g*259+c]; featflat = [sel_fine.ravel(), sel_coarse.ravel()]
  // sel_fine is (B, 2048, 256) point-major (numpy advanced-indexing puts index dims first)
  for (int task = t; task < 259 * 16; task += 256) {
    int c = task >> 4, p = task & 15;
    int g = g0 + p;
    int j = g * 259 + c;
    float v;
    if (j < 1048576) {
      int nsrc = j >> 8, ch = j & 255;
      int bs = nsrc >> 11;
      int lin = lin_sorted[nsrc];
      int h = lin >> 9, w = lin & 511;
      float sy = (h + 0.5f) * 0.5f - 0.5f;
      float sx = (w + 0.5f) * 0.5f - 0.5f;
      float yf = floorf(sy), xf = floorf(sx);
      float fy = sy - yf, fx = sx - xf;
      int yi = (int)yf, xi = (int)xf;
      int y0 = min(255, max(0, yi)), y1 = min(255, max(0, yi + 1));
      int x0 = min(255, max(0, xi)), x1 = min(255, max(0, xi + 1));
      const float* base = fine + (((size_t)(bs * 256 + ch)) << 16);
      float v00 = base[(y0 << 8) + x0];
      float v01 = base[(y0 << 8) + x1];
      float v10 = base[(y1 << 8) + x0];
      float v11 = base[(y1 << 8) + x1];
      v = (1.0f - fy) * ((1.0f - fx) * v00 + fx * v01) + fy * ((1.0f - fx) * v10 + fx * v11);
    } else {
      int jj = j - 1048576;
      int nsrc = jj / 3;
      int kk = jj - nsrc * 3;
      int bs = nsrc >> 11;
      int lin = lin_sorted[nsrc];
      int h = lin >> 9, w = lin & 511;
      float fy, fx; int y0, y1, x0, x1;
      coarse_coords(h, w, fy, fx, y0, y1, x0, x1);
      v = coarse_sample(coarse + (((size_t)bs * 3 + kk) << 14), fy, fx, y0, y1, x0, x1);
    }
    xs[c][p] = v;
  }
  __syncthreads();

  // layer 1: 259 -> 256, thread computes 4 outputs x 4 points
  {
    const int ob = (t & 63) * 4;
    const int pb = (t >> 6) * 4;
    float acc[4][4];
#pragma unroll
    for (int i = 0; i < 4; ++i)
#pragma unroll
      for (int q = 0; q < 4; ++q) acc[i][q] = 0.0f;
    const float* wr = w1 + ob * 259;
    for (int c = 0; c < 259; ++c) {
      const float4 xv = *(const float4*)&xs[c][pb];
      float wv0 = wr[c];
      float wv1 = wr[c + 259];
      float wv2 = wr[c + 518];
      float wv3 = wr[c + 777];
      acc[0][0] = fmaf(wv0, xv.x, acc[0][0]); acc[0][1] = fmaf(wv0, xv.y, acc[0][1]);
      acc[0][2] = fmaf(wv0, xv.z, acc[0][2]); acc[0][3] = fmaf(wv0, xv.w, acc[0][3]);
      acc[1][0] = fmaf(wv1, xv.x, acc[1][0]); acc[1][1] = fmaf(wv1, xv.y, acc[1][1]);
      acc[1][2] = fmaf(wv1, xv.z, acc[1][2]); acc[1][3] = fmaf(wv1, xv.w, acc[1][3]);
      acc[2][0] = fmaf(wv2, xv.x, acc[2][0]); acc[2][1] = fmaf(wv2, xv.y, acc[2][1]);
      acc[2][2] = fmaf(wv2, xv.z, acc[2][2]); acc[2][3] = fmaf(wv2, xv.w, acc[2][3]);
      acc[3][0] = fmaf(wv3, xv.x, acc[3][0]); acc[3][1] = fmaf(wv3, xv.y, acc[3][1]);
      acc[3][2] = fmaf(wv3, xv.z, acc[3][2]); acc[3][3] = fmaf(wv3, xv.w, acc[3][3]);
    }
#pragma unroll
    for (int i = 0; i < 4; ++i) {
      l1t[ob + i][pb + 0] = prelu_f(acc[i][0], a);
      l1t[ob + i][pb + 1] = prelu_f(acc[i][1], a);
      l1t[ob + i][pb + 2] = prelu_f(acc[i][2], a);
      l1t[ob + i][pb + 3] = prelu_f(acc[i][3], a);
    }
  }
  __syncthreads();

  // layer 2: (256 + 3 tail) -> 128, thread computes 4 outputs x 2 points
  {
    const int ob = (t & 31) * 4;
    const int pb = (t >> 5) * 2;
    float acc[4][2];
#pragma unroll
    for (int i = 0; i < 4; ++i) { acc[i][0] = 0.0f; acc[i][1] = 0.0f; }
    const float* wr = w2 + ob * 259;
    for (int c = 0; c < 256; ++c) {
      const float2 xv = *(const float2*)&l1t[c][pb];
      float wv0 = wr[c];
      float wv1 = wr[c + 259];
      float wv2 = wr[c + 518];
      float wv3 = wr[c + 777];
      acc[0][0] = fmaf(wv0, xv.x, acc[0][0]); acc[0][1] = fmaf(wv0, xv.y, acc[0][1]);
      acc[1][0] = fmaf(wv1, xv.x, acc[1][0]); acc[1][1] = fmaf(wv1, xv.y, acc[1][1]);
      acc[2][0] = fmaf(wv2, xv.x, acc[2][0]); acc[2][1] = fmaf(wv2, xv.y, acc[2][1]);
      acc[3][0] = fmaf(wv3, xv.x, acc[3][0]); acc[3][1] = fmaf(wv3, xv.y, acc[3][1]);
    }
#pragma unroll
    for (int kk = 0; kk < 3; ++kk) {
      const float x0 = xs[256 + kk][pb], x1 = xs[256 + kk][pb + 1];
      float wv0 = wr[256 + kk];
      float wv1 = wr[256 + kk + 259];
      float wv2 = wr[256 + kk + 518];
      float wv3 = wr[256 + kk + 777];
      acc[0][0] = fmaf(wv0, x0, acc[0][0]); acc[0][1] = fmaf(wv0, x1, acc[0][1]);
      acc[1][0] = fmaf(wv1, x0, acc[1][0]); acc[1][1] = fmaf(wv1, x1, acc[1][1]);
      acc[2][0] = fmaf(wv2, x0, acc[2][0]); acc[2][1] = fmaf(wv2, x1, acc[2][1]);
      acc[3][0] = fmaf(wv3, x0, acc[3][0]); acc[3][1] = fmaf(wv3, x1, acc[3][1]);
    }
#pragma unroll
    for (int i = 0; i < 4; ++i) {
      l2t[ob + i][pb + 0] = prelu_f(acc[i][0], a);
      l2t[ob + i][pb + 1] = prelu_f(acc[i][1], a);
    }
  }
  __syncthreads();

  // layer 3: (128 + 3 tail) -> 3
  if (t < 48) {
    const int o3 = t % 3, p = t / 3;
    const float* wr = w3 + o3 * 131;
    float s = 0.0f;
    for (int c = 0; c < 128; ++c) s = fmaf(wr[c], l2t[c][p], s);
#pragma unroll
    for (int kk = 0; kk < 3; ++kk) s = fmaf(wr[128 + kk], xs[256 + kk][p], s);
    const int g = g0 + p;
    out[((g >> 11) * 3 + o3) * 2048 + (g & 2047)] = s;
  }
}

extern "C" void kernel_launch(void* const* d_in, const int* in_sizes, int n_in,
                              void* d_out, int out_size, void* d_ws, size_t ws_size,
                              hipStream_t stream) {
  const float* fine   = (const float*)d_in[0];
  const float* coarse = (const float*)d_in[1];
  const float* w1     = (const float*)d_in[2];
  const float* w2     = (const float*)d_in[3];
  const float* w3     = (const float*)d_in[4];
  const float* pa     = (const float*)d_in[5];
  const int*   ridx   = (const int*)d_in[6];

  float* out  = (float*)d_out;
  float* mask = out + 2 * 3 * 2048;    // f32 element 12288 -> byte offset 49152 (16B aligned)
  int* lin_sorted = (int*)d_ws;        // 4096 ints

  // zero the mask region (2*512*512 f32 = 2 MB) -> 131072 uint4 stores
  pr_fill_v3<<<512, 256, 0, stream>>>((uint4*)mask);
  // per-batch uncertainty + exact top-1536 + sort + mask scatter
  pr_select_v3<<<2, 1024, 0, stream>>>(coarse, ridx, lin_sorted, mask);
  // fused gather + MLP
  pr_mlp_v3<<<256, 256, 0, stream>>>(fine, coarse, w1, w2, w3, pa, lin_sorted, out);
}

// Round 4
// 254.754 us; speedup vs baseline: 1.9400x; 1.9400x over previous
//
#include <hip/hip_runtime.h>
#include <hip/hip_bf16.h>

#define NPTS 2048
#define NOVER 6144
#define STEP1 1536
#define STEP2 512
#define HW_TOT 262144

__device__ __forceinline__ float prelu_f(float x, float a) { return x >= 0.0f ? x : a * x; }

// coarse (128x128) bilinear coords for 512-output half-pixel sampling
__device__ __forceinline__ void coarse_coords(int h, int w, float& fy, float& fx,
                                              int& y0, int& y1, int& x0, int& x1) {
  float sy = (h + 0.5f) * 0.25f - 0.5f;
  float sx = (w + 0.5f) * 0.25f - 0.5f;
  float yf = floorf(sy), xf = floorf(sx);
  fy = sy - yf; fx = sx - xf;
  int yi = (int)yf, xi = (int)xf;
  y0 = min(127, max(0, yi)); y1 = min(127, max(0, yi + 1));
  x0 = min(127, max(0, xi)); x1 = min(127, max(0, xi + 1));
}

__device__ __forceinline__ float coarse_sample(const float* __restrict__ ch, float fy, float fx,
                                               int y0, int y1, int x0, int x1) {
  float v00 = ch[(y0 << 7) + x0];
  float v01 = ch[(y0 << 7) + x1];
  float v10 = ch[(y1 << 7) + x0];
  float v11 = ch[(y1 << 7) + x1];
  return (1.0f - fy) * ((1.0f - fx) * v00 + fx * v01) + fy * ((1.0f - fx) * v10 + fx * v11);
}

// zero the f32 mask region (2*512*512 floats = 2 MB) -> 131072 uint4 stores
__global__ __launch_bounds__(256) void pr_fill_v4(uint4* __restrict__ p) {
  p[blockIdx.x * 256 + threadIdx.x] = make_uint4(0u, 0u, 0u, 0u);
}

// transpose w1 (256x259) -> wT1 (259x256), w2 (128x259) -> wT2 (259x128)
__global__ __launch_bounds__(256) void pr_wprep_v4(const float* __restrict__ w1,
                                                   const float* __restrict__ w2,
                                                   float* __restrict__ wT1,
                                                   float* __restrict__ wT2) {
  int gid = blockIdx.x * 256 + threadIdx.x;
  if (gid < 259 * 256) {
    int c = gid >> 8, o = gid & 255;
    wT1[c * 256 + o] = w1[o * 259 + c];
  } else {
    int g2 = gid - 259 * 256;
    if (g2 < 259 * 128) {
      int c = g2 >> 7, o = g2 & 127;
      wT2[c * 128 + o] = w2[o * 259 + c];
    }
  }
}

// uncertainty keys for 2*6144 candidates (monotone u32 encoding of u in (0,1])
__global__ __launch_bounds__(256) void pr_uncert_v4(const float* __restrict__ coarse,
                                                    const int* __restrict__ ridx,
                                                    unsigned* __restrict__ keys) {
  int gid = blockIdx.x * 256 + threadIdx.x;
  if (gid >= 2 * NOVER) return;
  int b = gid / NOVER, i = gid - b * NOVER;
  int lin = ridx[i];
  int h = lin >> 9, w = lin & 511;
  float fy, fx; int y0, y1, x0, x1;
  coarse_coords(h, w, fy, fx, y0, y1, x0, x1);
  const float* cb = coarse + (((size_t)b * 3) << 14);
  float p0 = coarse_sample(cb, fy, fx, y0, y1, x0, x1);
  float p1 = coarse_sample(cb + (1 << 14), fy, fx, y0, y1, x0, x1);
  float p2 = coarse_sample(cb + (2 << 14), fy, fx, y0, y1, x0, x1);
  float m = fmaxf(p0, fmaxf(p1, p2));
  float e0 = expf(p0 - m), e1 = expf(p1 - m), e2 = expf(p2 - m);
  float s = e0 + e1 + e2;
  float q0 = e0 / s, q1 = e1 / s, q2 = e2 / s;
  float a0 = q0, a1 = q1, a2 = q2, tmp;
  if (a0 < a1) { tmp = a0; a0 = a1; a1 = tmp; }
  if (a1 < a2) { tmp = a1; a1 = a2; a2 = tmp; }
  if (a0 < a1) { tmp = a0; a0 = a1; a1 = tmp; }
  float u = 1.0f - (a0 - a1);   // strictly positive -> bit pattern is order-monotone
  keys[gid] = __float_as_uint(u);
}

// One block per batch: exact radix-select top-1536 (val desc, idx asc tie-break),
// mask scatter, and bitmap-based ascending sort of the 2048 selected lins.
__global__ __launch_bounds__(1024) void pr_topk_v4(const unsigned* __restrict__ keys,
                                                   const int* __restrict__ ridx,
                                                   int* __restrict__ lin_sorted,
                                                   float* __restrict__ mask) {
  __shared__ unsigned kv[NOVER];            // 24 KB
  __shared__ unsigned bitmap[8192];         // 32 KB (262144 bits)
  __shared__ unsigned hist[256];
  __shared__ unsigned short tiebuf[NOVER];  // 12 KB (worst-case ties)
  __shared__ unsigned scanbuf[16];
  __shared__ unsigned selinfo[2];           // [0]=prefix/T, [1]=R
  __shared__ int tiecnt;
  const int b = blockIdx.x, t = threadIdx.x;
  const int lane = t & 63, wid = t >> 6;

  for (int i = t; i < NOVER; i += 1024) kv[i] = keys[b * NOVER + i];
  for (int i = t; i < 8192; i += 1024) bitmap[i] = 0u;
  if (t == 0) { selinfo[1] = STEP1; tiecnt = 0; }
  __syncthreads();

  // 4-pass radix select (descending): find exact threshold T and tie-rank r
  unsigned prefix = 0u;
  for (int pass = 0; pass < 4; ++pass) {
    const int shift = 24 - 8 * pass;
    const unsigned maskHi = (pass == 0) ? 0u : (0xFFFFFFFFu << (shift + 8));
    for (int i = t; i < 256; i += 1024) hist[i] = 0u;
    __syncthreads();
    for (int i = t; i < NOVER; i += 1024) {
      unsigned k = kv[i];
      if ((k & maskHi) == prefix) atomicAdd(&hist[(k >> shift) & 255u], 1u);
    }
    __syncthreads();
    if (t < 64) {  // one wave: suffix scan over 256 bins (4 bins/lane)
      unsigned h0 = hist[t * 4], h1 = hist[t * 4 + 1], h2 = hist[t * 4 + 2], h3 = hist[t * 4 + 3];
      unsigned q = h0 + h1 + h2 + h3;
      unsigned s = q;
      for (int off = 1; off < 64; off <<= 1) {
        unsigned n = __shfl_down(s, off);
        if (t + off < 64) s += n;
      }
      unsigned exq = s - q;                    // count in strictly-higher quads
      unsigned R = selinfo[1];                 // lockstep: all lanes read before any write
      unsigned se3 = exq, se2 = se3 + h3, se1 = se2 + h2, se0 = se1 + h1;
      if (se3 < R && R <= se3 + h3)      { selinfo[0] = prefix | ((unsigned)(t * 4 + 3) << shift); selinfo[1] = R - se3; }
      else if (se2 < R && R <= se2 + h2) { selinfo[0] = prefix | ((unsigned)(t * 4 + 2) << shift); selinfo[1] = R - se2; }
      else if (se1 < R && R <= se1 + h1) { selinfo[0] = prefix | ((unsigned)(t * 4 + 1) << shift); selinfo[1] = R - se1; }
      else if (se0 < R && R <= se0 + h0) { selinfo[0] = prefix | ((unsigned)(t * 4 + 0) << shift); selinfo[1] = R - se0; }
    }
    __syncthreads();
    prefix = selinfo[0];
  }
  const unsigned T = prefix;
  const int r = (int)selinfo[1];   // take r smallest-index items among key==T

  // selection pass: key > T definitely in; ties collected
  for (int i = t; i < NOVER; i += 1024) {
    unsigned k = kv[i];
    if (k > T) {
      int lin = ridx[i];
      mask[(size_t)b * HW_TOT + lin] = 1.0f;
      atomicOr(&bitmap[lin >> 5], 1u << (lin & 31));
    } else if (k == T) {
      int pos = atomicAdd(&tiecnt, 1);
      tiebuf[pos] = (unsigned short)i;
    }
  }
  // coverage points (last 512 of the permutation; disjoint from candidates)
  for (int i = t; i < STEP2; i += 1024) {
    int lin = ridx[HW_TOT - STEP2 + i];
    mask[(size_t)b * HW_TOT + lin] = 1.0f;
    atomicOr(&bitmap[lin >> 5], 1u << (lin & 31));
  }
  __syncthreads();
  const int m = tiecnt;
  for (int j = t; j < m; j += 1024) {
    int idx = tiebuf[j];
    int rank = 0;
    for (int jj = 0; jj < m; ++jj) rank += (tiebuf[jj] < idx) ? 1 : 0;
    if (rank < r) {
      int lin = ridx[idx];
      mask[(size_t)b * HW_TOT + lin] = 1.0f;
      atomicOr(&bitmap[lin >> 5], 1u << (lin & 31));
    }
  }
  __syncthreads();

  // bitmap -> ascending lin_sorted via popcount prefix scan (2048 set bits exactly)
  unsigned mySum = 0;
#pragma unroll
  for (int q = 0; q < 8; ++q) mySum += __popc(bitmap[t * 8 + q]);
  unsigned v = mySum;
  for (int off = 1; off < 64; off <<= 1) {
    unsigned n = __shfl_up(v, off);
    if (lane >= off) v += n;
  }
  if (lane == 63) scanbuf[wid] = v;
  __syncthreads();
  if (t == 0) {
    unsigned run = 0;
    for (int w16 = 0; w16 < 16; ++w16) { unsigned tmp = scanbuf[w16]; scanbuf[w16] = run; run += tmp; }
  }
  __syncthreads();
  unsigned pos = (v - mySum) + scanbuf[wid];
  for (int q = 0; q < 8; ++q) {
    unsigned word = bitmap[t * 8 + q];
    int basebit = (t * 8 + q) << 5;
    while (word) {
      int bit = __ffs(word) - 1;
      word &= word - 1;
      lin_sorted[b * NPTS + pos++] = basebit + bit;
    }
  }
}

// Fused gather (reference's flatten-concat-reshape feat layout) + 3-layer MLP.
// Weights read from ws-transposed wT1/wT2 -> coalesced 1 KB float4 wave loads.
__global__ __launch_bounds__(256) void pr_mlp_v4(const float* __restrict__ fine,
                                                 const float* __restrict__ coarse,
                                                 const float* __restrict__ wT1,
                                                 const float* __restrict__ wT2,
                                                 const float* __restrict__ w3,
                                                 const float* __restrict__ pa,
                                                 const int* __restrict__ lin_sorted,
                                                 float* __restrict__ out) {
  __shared__ __align__(16) float xs[259][16];
  __shared__ __align__(16) float l1t[256][16];
  __shared__ __align__(16) float l2t[128][16];
  const int t = threadIdx.x;
  const int g0 = blockIdx.x * 16;
  const float a = pa[0];

  // gather: x[c] of group g == featflat[g*259+c]; featflat = [sel_fine.ravel(), sel_coarse.ravel()]
  for (int task = t; task < 259 * 16; task += 256) {
    int c = task >> 4, p = task & 15;
    int g = g0 + p;
    int j = g * 259 + c;
    float v;
    if (j < 1048576) {
      int nsrc = j >> 8, ch = j & 255;
      int bs = nsrc >> 11;
      int lin = lin_sorted[nsrc];
      int h = lin >> 9, w = lin & 511;
      float sy = (h + 0.5f) * 0.5f - 0.5f;
      float sx = (w + 0.5f) * 0.5f - 0.5f;
      float yf = floorf(sy), xf = floorf(sx);
      float fy = sy - yf, fx = sx - xf;
      int yi = (int)yf, xi = (int)xf;
      int y0 = min(255, max(0, yi)), y1 = min(255, max(0, yi + 1));
      int x0 = min(255, max(0, xi)), x1 = min(255, max(0, xi + 1));
      const float* base = fine + (((size_t)(bs * 256 + ch)) << 16);
      float v00 = base[(y0 << 8) + x0];
      float v01 = base[(y0 << 8) + x1];
      float v10 = base[(y1 << 8) + x0];
      float v11 = base[(y1 << 8) + x1];
      v = (1.0f - fy) * ((1.0f - fx) * v00 + fx * v01) + fy * ((1.0f - fx) * v10 + fx * v11);
    } else {
      int jj = j - 1048576;
      int nsrc = jj / 3;
      int kk = jj - nsrc * 3;
      int bs = nsrc >> 11;
      int lin = lin_sorted[nsrc];
      int h = lin >> 9, w = lin & 511;
      float fy, fx; int y0, y1, x0, x1;
      coarse_coords(h, w, fy, fx, y0, y1, x0, x1);
      v = coarse_sample(coarse + (((size_t)bs * 3 + kk) << 14), fy, fx, y0, y1, x0, x1);
    }
    xs[c][p] = v;
  }
  __syncthreads();

  // layer 1: 259 -> 256; thread = 4 outs (lane-quad, coalesced weights) x 4 points
  {
    const int ob = (t & 63) * 4;
    const int pb = (t >> 6) * 4;
    float acc[4][4];
#pragma unroll
    for (int i = 0; i < 4; ++i)
#pragma unroll
      for (int q = 0; q < 4; ++q) acc[i][q] = 0.0f;
    for (int c = 0; c < 259; ++c) {
      const float4 wv = *(const float4*)&wT1[c * 256 + ob];   // 64 lanes -> 1 KB contiguous
      const float4 xv = *(const float4*)&xs[c][pb];           // wave-uniform broadcast
      acc[0][0] = fmaf(wv.x, xv.x, acc[0][0]); acc[0][1] = fmaf(wv.x, xv.y, acc[0][1]);
      acc[0][2] = fmaf(wv.x, xv.z, acc[0][2]); acc[0][3] = fmaf(wv.x, xv.w, acc[0][3]);
      acc[1][0] = fmaf(wv.y, xv.x, acc[1][0]); acc[1][1] = fmaf(wv.y, xv.y, acc[1][1]);
      acc[1][2] = fmaf(wv.y, xv.z, acc[1][2]); acc[1][3] = fmaf(wv.y, xv.w, acc[1][3]);
      acc[2][0] = fmaf(wv.z, xv.x, acc[2][0]); acc[2][1] = fmaf(wv.z, xv.y, acc[2][1]);
      acc[2][2] = fmaf(wv.z, xv.z, acc[2][2]); acc[2][3] = fmaf(wv.z, xv.w, acc[2][3]);
      acc[3][0] = fmaf(wv.w, xv.x, acc[3][0]); acc[3][1] = fmaf(wv.w, xv.y, acc[3][1]);
      acc[3][2] = fmaf(wv.w, xv.z, acc[3][2]); acc[3][3] = fmaf(wv.w, xv.w, acc[3][3]);
    }
#pragma unroll
    for (int i = 0; i < 4; ++i) {
      l1t[ob + i][pb + 0] = prelu_f(acc[i][0], a);
      l1t[ob + i][pb + 1] = prelu_f(acc[i][1], a);
      l1t[ob + i][pb + 2] = prelu_f(acc[i][2], a);
      l1t[ob + i][pb + 3] = prelu_f(acc[i][3], a);
    }
  }
  __syncthreads();

  // layer 2: (256 + 3 tail) -> 128; thread = 4 outs x 2 points
  {
    const int ob = (t & 31) * 4;
    const int pb = (t >> 5) * 2;
    float acc[4][2];
#pragma unroll
    for (int i = 0; i < 4; ++i) { acc[i][0] = 0.0f; acc[i][1] = 0.0f; }
    for (int c = 0; c < 256; ++c) {
      const float4 wv = *(const float4*)&wT2[c * 128 + ob];
      const float2 xv = *(const float2*)&l1t[c][pb];
      acc[0][0] = fmaf(wv.x, xv.x, acc[0][0]); acc[0][1] = fmaf(wv.x, xv.y, acc[0][1]);
      acc[1][0] = fmaf(wv.y, xv.x, acc[1][0]); acc[1][1] = fmaf(wv.y, xv.y, acc[1][1]);
      acc[2][0] = fmaf(wv.z, xv.x, acc[2][0]); acc[2][1] = fmaf(wv.z, xv.y, acc[2][1]);
      acc[3][0] = fmaf(wv.w, xv.x, acc[3][0]); acc[3][1] = fmaf(wv.w, xv.y, acc[3][1]);
    }
#pragma unroll
    for (int kk = 0; kk < 3; ++kk) {
      const float4 wv = *(const float4*)&wT2[(256 + kk) * 128 + ob];
      const float x0 = xs[256 + kk][pb], x1 = xs[256 + kk][pb + 1];
      acc[0][0] = fmaf(wv.x, x0, acc[0][0]); acc[0][1] = fmaf(wv.x, x1, acc[0][1]);
      acc[1][0] = fmaf(wv.y, x0, acc[1][0]); acc[1][1] = fmaf(wv.y, x1, acc[1][1]);
      acc[2][0] = fmaf(wv.z, x0, acc[2][0]); acc[2][1] = fmaf(wv.z, x1, acc[2][1]);
      acc[3][0] = fmaf(wv.w, x0, acc[3][0]); acc[3][1] = fmaf(wv.w, x1, acc[3][1]);
    }
#pragma unroll
    for (int i = 0; i < 4; ++i) {
      l2t[ob + i][pb + 0] = prelu_f(acc[i][0], a);
      l2t[ob + i][pb + 1] = prelu_f(acc[i][1], a);
    }
  }
  __syncthreads();

  // layer 3: (128 + 3 tail) -> 3
  if (t < 48) {
    const int o3 = t % 3, p = t / 3;
    const float* wr = w3 + o3 * 131;
    float s = 0.0f;
    for (int c = 0; c < 128; ++c) s = fmaf(wr[c], l2t[c][p], s);
#pragma unroll
    for (int kk = 0; kk < 3; ++kk) s = fmaf(wr[128 + kk], xs[256 + kk][p], s);
    const int g = g0 + p;
    out[((g >> 11) * 3 + o3) * 2048 + (g & 2047)] = s;
  }
}

extern "C" void kernel_launch(void* const* d_in, const int* in_sizes, int n_in,
                              void* d_out, int out_size, void* d_ws, size_t ws_size,
                              hipStream_t stream) {
  const float* fine   = (const float*)d_in[0];
  const float* coarse = (const float*)d_in[1];
  const float* w1     = (const float*)d_in[2];
  const float* w2     = (const float*)d_in[3];
  const float* w3     = (const float*)d_in[4];
  const float* pa     = (const float*)d_in[5];
  const int*   ridx   = (const int*)d_in[6];

  float* out  = (float*)d_out;
  float* mask = out + 2 * 3 * 2048;            // f32 elem 12288, byte 49152 (16B aligned)

  char* ws = (char*)d_ws;
  int*      lin_sorted = (int*)ws;                              // 16384 B
  float*    wT1  = (float*)(ws + 16384);                        // 265216 B (259x256 f32)
  float*    wT2  = (float*)(ws + 16384 + 265216);               // 132608 B (259x128 f32)
  unsigned* keys = (unsigned*)(ws + 16384 + 265216 + 132608);   // 49152 B (2x6144 u32)

  pr_fill_v4<<<512, 256, 0, stream>>>((uint4*)mask);
  pr_wprep_v4<<<389, 256, 0, stream>>>(w1, w2, wT1, wT2);
  pr_uncert_v4<<<48, 256, 0, stream>>>(coarse, ridx, keys);
  pr_topk_v4<<<2, 1024, 0, stream>>>(keys, ridx, lin_sorted, mask);
  pr_mlp_v4<<<256, 256, 0, stream>>>(fine, coarse, wT1, wT2, w3, pa, lin_sorted, out);
}